// Round 1
// baseline (1881.711 us; speedup 1.0000x reference)
//
#include <hip/hip_runtime.h>
#include <math.h>

// Problem constants (fixed by setup_inputs)
#define BATCH 16
#define TMAX  256
#define UU    64      // label length U
#define U1    65      // U+1
#define V1    513     // vocab+blank
#define BLANKI 512

__device__ __forceinline__ float logaddexpf_(float a, float b) {
    float m = fmaxf(a, b);
    float d = fabsf(a - b);
    return m + log1pf(__expf(-d));
}

// Kernel 1: one wave per (b,t,u) cell. logsumexp over 513 logits,
// emit blank_lp[b,t,u] and lab_lp[b,t,u] (u<U).
__global__ __launch_bounds__(256) void lse_kernel(const float* __restrict__ logits,
                                                  const int* __restrict__ y,
                                                  float* __restrict__ blank_lp,
                                                  float* __restrict__ lab_lp) {
    const int wave = (blockIdx.x * blockDim.x + threadIdx.x) >> 6;
    const int lane = threadIdx.x & 63;
    const int ncells = BATCH * TMAX * U1;
    if (wave >= ncells) return;

    const long long base = (long long)wave * V1;

    // 513 = 8*64 + 1. Coalesced stride-64 dword loads.
    float v[8];
#pragma unroll
    for (int k = 0; k < 8; ++k) v[k] = logits[base + lane + (k << 6)];
    float vb = (lane == 0) ? logits[base + BLANKI] : -INFINITY;

    float m = vb;
#pragma unroll
    for (int k = 0; k < 8; ++k) m = fmaxf(m, v[k]);
#pragma unroll
    for (int off = 32; off; off >>= 1) m = fmaxf(m, __shfl_xor(m, off));

    float s = (lane == 0) ? __expf(vb - m) : 0.0f;
#pragma unroll
    for (int k = 0; k < 8; ++k) s += __expf(v[k] - m);
#pragma unroll
    for (int off = 32; off; off >>= 1) s += __shfl_xor(s, off);

    const float lse = m + __logf(s);

    if (lane == 0) {
        const int u  = wave % U1;
        const int bt = wave / U1;          // b*TMAX + t
        const int b  = bt / TMAX;
        blank_lp[wave] = vb - lse;
        if (u < UU) {
            const int label = y[b * UU + u];
            lab_lp[bt * UU + u] = logits[base + label] - lse;  // L1/L2-hot gather
        }
    }
}

// Kernel 2: one wave per sequence (16 waves, 1 block). Alpha recurrence using
// the reference's closed form:
//   base = prev + blank_row;  c = exclusive-cumsum(lab_row)
//   a[u] = c[u] + logcumsumexp(base - c)[u]
// Lane u holds column u (u=0..63); column 64 is a replicated scalar.
__global__ __launch_bounds__(1024) void alpha_kernel(const float* __restrict__ blank_lp,
                                                     const float* __restrict__ lab_lp,
                                                     const int* __restrict__ logit_lens,
                                                     const int* __restrict__ y_lens,
                                                     float* __restrict__ out) {
    __shared__ float losses[BATCH];
    const int wave = threadIdx.x >> 6;
    const int lane = threadIdx.x & 63;
    const int b = wave;

    const float* __restrict__ blk = blank_lp + (long long)b * TMAX * U1;
    const float* __restrict__ lab = lab_lp   + (long long)b * TMAX * UU;
    const int Tl = logit_lens[b];
    const int Ul = y_lens[b];

    // row 0: alpha[0,u] = sum_{j<u} lab[0,j]
    float inc = lab[lane];
#pragma unroll
    for (int off = 1; off < 64; off <<= 1) {
        float o = __shfl_up(inc, off);
        if (lane >= off) inc += o;
    }
    float a64 = __shfl(inc, 63);           // alpha[0,64]
    float a = __shfl_up(inc, 1);
    if (lane == 0) a = 0.0f;               // alpha[0,lane]

    for (int t = 1; t < Tl; ++t) {
        const float bprev   = blk[(t - 1) * U1 + lane];
        const float bprev64 = blk[(t - 1) * U1 + 64];
        const float labr    = lab[t * UU + lane];

        const float base   = a + bprev;
        const float base64 = a64 + bprev64;

        // exclusive cumsum of lab row
        float inc2 = labr;
#pragma unroll
        for (int off = 1; off < 64; off <<= 1) {
            float o = __shfl_up(inc2, off);
            if (lane >= off) inc2 += o;
        }
        const float ctot = __shfl(inc2, 63);
        float c = __shfl_up(inc2, 1);
        if (lane == 0) c = 0.0f;

        // inclusive logcumsumexp scan of (base - c)
        float L = base - c;
#pragma unroll
        for (int off = 1; off < 64; off <<= 1) {
            float o = __shfl_up(L, off);
            if (lane >= off) L = logaddexpf_(L, o);
        }
        a = c + L;

        const float L63 = __shfl(L, 63);
        const float g64 = base64 - ctot;
        a64 = ctot + logaddexpf_(L63, g64);
    }

    // ll = alpha[Tl-1, Ul] + blank_lp[Tl-1, Ul]
    float aU = (Ul < UU) ? __shfl(a, Ul) : a64;
    const float blast = blk[(Tl - 1) * U1 + Ul];
    if (lane == 0) losses[b] = -(aU + blast);

    __syncthreads();
    if (threadIdx.x == 0) {
        float s = 0.0f;
        for (int i = 0; i < BATCH; ++i) s += losses[i];
        out[0] = s * (1.0f / BATCH);
    }
}

extern "C" void kernel_launch(void* const* d_in, const int* in_sizes, int n_in,
                              void* d_out, int out_size, void* d_ws, size_t ws_size,
                              hipStream_t stream) {
    const float* logits     = (const float*)d_in[0];
    const int*   logit_lens = (const int*)d_in[1];
    const int*   y          = (const int*)d_in[2];
    const int*   y_lens     = (const int*)d_in[3];
    float* out = (float*)d_out;

    float* blank_lp = (float*)d_ws;                          // B*T*65 floats
    float* lab_lp   = blank_lp + BATCH * TMAX * U1;          // B*T*64 floats

    const int ncells = BATCH * TMAX * U1;                    // 266240 waves
    const int grid = (ncells + 3) / 4;                       // 4 waves/block
    lse_kernel<<<grid, 256, 0, stream>>>(logits, y, blank_lp, lab_lp);
    alpha_kernel<<<1, 1024, 0, stream>>>(blank_lp, lab_lp, logit_lens, y_lens, out);
}

// Round 2
// 1263.583 us; speedup vs baseline: 1.4892x; 1.4892x over previous
//
#include <hip/hip_runtime.h>
#include <math.h>

// Problem constants (fixed by setup_inputs)
#define BATCH 16
#define TMAX  256
#define UU    64      // label length U
#define U1    65      // U+1
#define V1    513     // vocab+blank
#define BLANKI 512
#define NEG_INF (-INFINITY)

__device__ __forceinline__ float logaddexpf_(float a, float b) {
    float m = fmaxf(a, b);
    float d = fabsf(a - b);
    return m + log1pf(__expf(-d));
}

__device__ __forceinline__ int clampi(int x, int lo, int hi) {
    return min(max(x, lo), hi);
}

// Kernel 1: one wave per (b,t,u) cell. logsumexp over 513 logits,
// emit blank_lp[b,t,u] and lab_lp[b,t,u] (u<U).
// Cells with t >= T_len or u > U_len are never read by the recurrence -> skip
// before any global load (saves ~45% of HBM traffic on average).
__global__ __launch_bounds__(256) void lse_kernel(const float* __restrict__ logits,
                                                  const int* __restrict__ y,
                                                  const int* __restrict__ logit_lens,
                                                  const int* __restrict__ y_lens,
                                                  float* __restrict__ blank_lp,
                                                  float* __restrict__ lab_lp) {
    const int wave = (blockIdx.x * blockDim.x + threadIdx.x) >> 6;
    const int lane = threadIdx.x & 63;
    const int ncells = BATCH * TMAX * U1;
    if (wave >= ncells) return;

    const int u  = wave % U1;
    const int bt = wave / U1;          // b*TMAX + t
    const int b  = bt / TMAX;
    const int t  = bt - b * TMAX;
    if (t >= logit_lens[b] || u > y_lens[b]) return;   // dead cell: no loads

    const long long base = (long long)wave * V1;

    // 513 = 8*64 + 1. Coalesced stride-64 dword loads.
    float v[8];
#pragma unroll
    for (int k = 0; k < 8; ++k) v[k] = logits[base + lane + (k << 6)];
    float vb = (lane == 0) ? logits[base + BLANKI] : NEG_INF;

    float m = vb;
#pragma unroll
    for (int k = 0; k < 8; ++k) m = fmaxf(m, v[k]);
#pragma unroll
    for (int off = 32; off; off >>= 1) m = fmaxf(m, __shfl_xor(m, off));

    float s = (lane == 0) ? __expf(vb - m) : 0.0f;
#pragma unroll
    for (int k = 0; k < 8; ++k) s += __expf(v[k] - m);
#pragma unroll
    for (int off = 32; off; off >>= 1) s += __shfl_xor(s, off);

    const float lse = m + __logf(s);

    if (lane == 0) {
        blank_lp[wave] = vb - lse;
        if (u < UU) {
            const int label = y[b * UU + u];
            lab_lp[bt * UU + u] = logits[base + label] - lse;  // row is L1-hot
        }
    }
}

// Kernel 2: diagonal-wavefront alpha. One wave per sequence (16 waves, 1 block).
// Lane u holds alpha[d-u, u] on anti-diagonal d = t+u. Per step: one shfl_up,
// one logaddexp. Column u=64 is lane-uniform in a second register (a64).
//   alpha[t,u] = logaddexp(alpha[t-1,u] + blank[t-1,u],
//                          alpha[t,u-1] + lab[t,u-1])
// Invalid lanes carry -inf; NaN from logaddexp(-inf,-inf) only occurs on lanes
// that are immediately masked back to -inf.
__global__ __launch_bounds__(1024) void alpha_kernel(const float* __restrict__ blank_lp,
                                                     const float* __restrict__ lab_lp,
                                                     const int* __restrict__ logit_lens,
                                                     const int* __restrict__ y_lens,
                                                     float* __restrict__ out) {
    __shared__ float losses[BATCH];
    const int b    = threadIdx.x >> 6;
    const int lane = threadIdx.x & 63;

    const float* __restrict__ blk = blank_lp + (long long)b * TMAX * U1;
    const float* __restrict__ lab = lab_lp   + (long long)b * TMAX * UU;
    const int Tl = logit_lens[b];
    const int Ul = y_lens[b];
    const int dEnd = Tl - 1 + Ul;

    float a   = (lane == 0) ? 0.0f : NEG_INF;  // alpha[0,0] = 0
    float a64 = NEG_INF;

    const int lm1 = max(lane - 1, 0);

    // prefetch operands for d = 1 (addresses depend only on d and lane)
    float bl   = blk[clampi(1 - lane - 1, 0, TMAX - 1) * U1 + lane];
    float la   = lab[clampi(1 - lane,     0, TMAX - 1) * UU + lm1];
    float bl64 = blk[clampi(1 - 65, 0, TMAX - 1) * U1 + 64];
    float la63 = lab[clampi(1 - 64, 0, TMAX - 1) * UU + 63];

    for (int d = 1; d <= dEnd; ++d) {
        // prefetch operands for d+1 (independent of the recurrence chain)
        const int dn = d + 1;
        float bl_n   = blk[clampi(dn - lane - 1, 0, TMAX - 1) * U1 + lane];
        float la_n   = lab[clampi(dn - lane,     0, TMAX - 1) * UU + lm1];
        float bl64_n = blk[clampi(dn - 65, 0, TMAX - 1) * U1 + 64];
        float la63_n = lab[clampi(dn - 64, 0, TMAX - 1) * UU + 63];

        const float left = __shfl_up(a, 1);     // alpha[t, u-1]
        const float a63b = __shfl(a, 63);       // alpha[d-64, 63] (pre-update)

        const float up_in   = a + bl;           // -inf-safe
        const float left_in = (lane == 0) ? NEG_INF : left + la;
        const float val     = logaddexpf_(up_in, left_in);
        const int   t       = d - lane;
        a = (t >= 0 && t < Tl) ? val : NEG_INF;

        // column u = 64 (uniform across lanes)
        const int   t64 = d - 64;
        const float v64 = logaddexpf_(a64 + bl64, a63b + la63);
        a64 = (t64 >= 0 && t64 < Tl) ? v64 : NEG_INF;

        bl = bl_n; la = la_n; bl64 = bl64_n; la63 = la63_n;
    }

    // ll = alpha[Tl-1, Ul] + blank_lp[Tl-1, Ul]
    const float aU    = (Ul < 64) ? __shfl(a, Ul) : a64;
    const float blast = blk[(Tl - 1) * U1 + Ul];
    if (lane == 0) losses[b] = -(aU + blast);

    __syncthreads();
    if (threadIdx.x == 0) {
        float s = 0.0f;
        for (int i = 0; i < BATCH; ++i) s += losses[i];
        out[0] = s * (1.0f / BATCH);
    }
}

extern "C" void kernel_launch(void* const* d_in, const int* in_sizes, int n_in,
                              void* d_out, int out_size, void* d_ws, size_t ws_size,
                              hipStream_t stream) {
    const float* logits     = (const float*)d_in[0];
    const int*   logit_lens = (const int*)d_in[1];
    const int*   y          = (const int*)d_in[2];
    const int*   y_lens     = (const int*)d_in[3];
    float* out = (float*)d_out;

    float* blank_lp = (float*)d_ws;                          // B*T*65 floats
    float* lab_lp   = blank_lp + BATCH * TMAX * U1;          // B*T*64 floats

    const int ncells = BATCH * TMAX * U1;                    // 266240 waves
    const int grid = (ncells + 3) / 4;                       // 4 waves/block
    lse_kernel<<<grid, 256, 0, stream>>>(logits, y, logit_lens, y_lens,
                                         blank_lp, lab_lp);
    alpha_kernel<<<1, 1024, 0, stream>>>(blank_lp, lab_lp, logit_lens, y_lens, out);
}

// Round 3
// 791.859 us; speedup vs baseline: 2.3763x; 1.5957x over previous
//
#include <hip/hip_runtime.h>
#include <math.h>

// Problem constants (fixed by setup_inputs)
#define BATCH 16
#define TMAX  256
#define UU    64      // label length U
#define U1    65      // U+1
#define V1    513     // vocab+blank
#define BLANKI 512
#define NEG_INF (-INFINITY)

// Workspace layout (floats):
//   [0..16)                losses per sequence
//   blank slabs: per b, BLK_ROWS x U1, with BLK_PAD leading pad rows
//   lab   slabs: per b, LAB_ROWS x UU, with LAB_PAD leading pad rows
// Pads absorb out-of-range prefetch reads in alpha (poison values are finite
// and always masked to -inf before use).
#define BLK_PAD  64
#define LAB_PAD  64
#define BLK_ROWS 384   // rows -64 .. 319
#define LAB_ROWS 392   // rows -64 .. 327
#define BLK_SLAB (BLK_ROWS * U1)
#define LAB_SLAB (LAB_ROWS * UU)
#define LOSS_OFF 0
#define BLK_OFF  16
#define LAB_OFF  (BLK_OFF + BATCH * BLK_SLAB)

__device__ __forceinline__ float lae(float x, float y) {
    // fast logaddexp; NaN only when both inputs are -inf (always masked after)
    float m = fmaxf(x, y);
    float z = fminf(x, y);
    return m + __logf(1.0f + __expf(z - m));
}

// Kernel 1: one wave per (b,t,u) cell. logsumexp over 513 logits,
// emit blank_lp and lab_lp into padded slabs. Dead cells (t >= T_len or
// u > U_len) exit before any load. 1024-thread blocks (16 waves) to cut
// block-dispatch count 4x vs round 2.
__global__ __launch_bounds__(1024) void lse_kernel(const float* __restrict__ logits,
                                                   const int* __restrict__ y,
                                                   const int* __restrict__ logit_lens,
                                                   const int* __restrict__ y_lens,
                                                   float* __restrict__ ws) {
    const int wave = (int)((blockIdx.x * 1024u + threadIdx.x) >> 6);
    const int lane = threadIdx.x & 63;
    const int ncells = BATCH * TMAX * U1;
    if (wave >= ncells) return;

    const int u  = wave % U1;
    const int bt = wave / U1;          // b*TMAX + t
    const int b  = bt / TMAX;
    const int t  = bt - b * TMAX;
    if (t >= logit_lens[b] || u > y_lens[b]) return;   // dead cell: no loads

    const long long base = (long long)wave * V1;

    // 513 = 8*64 + 1. Coalesced stride-64 dword loads sharing one base addr.
    float v[8];
#pragma unroll
    for (int k = 0; k < 8; ++k) v[k] = logits[base + lane + (k << 6)];
    float vb = (lane == 0) ? logits[base + BLANKI] : NEG_INF;

    float m = vb;
#pragma unroll
    for (int k = 0; k < 8; ++k) m = fmaxf(m, v[k]);
#pragma unroll
    for (int off = 32; off; off >>= 1) m = fmaxf(m, __shfl_xor(m, off));

    float s = (lane == 0) ? __expf(vb - m) : 0.0f;
#pragma unroll
    for (int k = 0; k < 8; ++k) s += __expf(v[k] - m);
#pragma unroll
    for (int off = 32; off; off >>= 1) s += __shfl_xor(s, off);

    const float lse = m + __logf(s);

    if (lane == 0) {
        float* blk = ws + BLK_OFF + b * BLK_SLAB + BLK_PAD * U1;
        blk[t * U1 + u] = vb - lse;
        if (u < UU) {
            float* lab = ws + LAB_OFF + b * LAB_SLAB + LAB_PAD * UU;
            const int label = y[b * UU + u];
            lab[t * UU + u] = logits[base + label] - lse;  // row is L1-hot
        }
    }
}

// Kernel 2: diagonal-wavefront alpha, one block (one wave, one CU) per
// sequence. Lane u holds alpha[d-u, u] on anti-diagonal d=t+u; column u=64
// is a lane-uniform register. Loads are pointer-increments into padded slabs
// (no clamps), prefetched one diagonal ahead.
__global__ __launch_bounds__(64) void alpha_kernel(const float* __restrict__ ws,
                                                   const int* __restrict__ logit_lens,
                                                   const int* __restrict__ y_lens,
                                                   float* __restrict__ losses) {
    const int b    = blockIdx.x;
    const int lane = threadIdx.x;

    const float* __restrict__ blk = ws + BLK_OFF + b * BLK_SLAB + BLK_PAD * U1;
    const float* __restrict__ lab = ws + LAB_OFF + b * LAB_SLAB + LAB_PAD * UU;
    const int Tl = logit_lens[b];
    const int Ul = y_lens[b];
    const int dEnd = Tl - 1 + Ul;

    float a   = (lane == 0) ? 0.0f : NEG_INF;  // alpha[0,0] = 0
    float a64 = NEG_INF;
    const int lm1 = (lane == 0) ? 0 : (lane - 1);

    // operand pointers for diagonal d=1; advance by one row per step
    const float* pb   = blk + (0 - lane) * U1 + lane;   // blank[d-1-lane, lane]
    const float* pl   = lab + (1 - lane) * UU + lm1;    // lab[d-lane, lane-1]
    const float* pb64 = blk + (1 - 65) * U1 + 64;       // blank[d-65, 64]
    const float* pl63 = lab + (1 - 64) * UU + 63;       // lab[d-64, 63]

    float bl   = *pb;
    float la   = *pl;
    float bl64 = *pb64;
    float la63 = *pl63;

    int dml = 1 - lane;   // d - lane
    for (int d = 1; d <= dEnd; ++d) {
        // prefetch operands for d+1 (independent of the recurrence chain)
        pb += U1; pl += UU; pb64 += U1; pl63 += UU;
        const float bl_n   = *pb;
        const float la_n   = *pl;
        const float bl64_n = *pb64;
        const float la63_n = *pl63;

        const float left = __shfl_up(a, 1);     // alpha[d-lane, lane-1]
        const float a63b = __shfl(a, 63);       // alpha[d-64, 63]

        const float up_in   = a + bl;
        const float left_in = (lane == 0) ? NEG_INF : (left + la);
        const float val     = lae(up_in, left_in);
        a = ((unsigned)dml < (unsigned)Tl) ? val : NEG_INF;

        const float v64 = lae(a64 + bl64, a63b + la63);
        a64 = ((unsigned)(d - 64) < (unsigned)Tl) ? v64 : NEG_INF;

        bl = bl_n; la = la_n; bl64 = bl64_n; la63 = la63_n;
        ++dml;
    }

    // ll = alpha[Tl-1, Ul] + blank_lp[Tl-1, Ul]
    const float aU    = (Ul < 64) ? __shfl(a, Ul) : a64;
    const float blast = blk[(Tl - 1) * U1 + Ul];
    if (lane == 0) losses[b] = -(aU + blast);
}

// Kernel 3: mean over the 16 per-sequence losses.
__global__ __launch_bounds__(64) void finalize_kernel(const float* __restrict__ losses,
                                                      float* __restrict__ out) {
    const int lane = threadIdx.x;
    float v = (lane < BATCH) ? losses[lane] : 0.0f;
#pragma unroll
    for (int off = 32; off; off >>= 1) v += __shfl_xor(v, off);
    if (lane == 0) out[0] = v * (1.0f / BATCH);
}

extern "C" void kernel_launch(void* const* d_in, const int* in_sizes, int n_in,
                              void* d_out, int out_size, void* d_ws, size_t ws_size,
                              hipStream_t stream) {
    const float* logits     = (const float*)d_in[0];
    const int*   logit_lens = (const int*)d_in[1];
    const int*   y          = (const int*)d_in[2];
    const int*   y_lens     = (const int*)d_in[3];
    float* out = (float*)d_out;
    float* ws  = (float*)d_ws;

    const int ncells = BATCH * TMAX * U1;                 // 266240 waves
    const int grid = (ncells + 15) / 16;                  // 16 waves/block
    lse_kernel<<<grid, 1024, 0, stream>>>(logits, y, logit_lens, y_lens, ws);
    alpha_kernel<<<BATCH, 64, 0, stream>>>(ws, logit_lens, y_lens, ws + LOSS_OFF);
    finalize_kernel<<<1, 64, 0, stream>>>(ws + LOSS_OFF, out);
}